// Round 1
// baseline (1303.763 us; speedup 1.0000x reference)
//
#include <hip/hip_runtime.h>

#define DF 128  // feature dim

// ---------------------------------------------------------------- utilities
static __device__ __forceinline__ float lrelu(float x) {
  return x > 0.f ? x : 0.1f * x;
}

// Detect whether edge_index buffer is int64 (odd 32-bit words all zero) or int32.
__global__ void detect64_kernel(const unsigned int* __restrict__ u, int E,
                                int* __restrict__ flag) {
  __shared__ int any32;
  if (threadIdx.x == 0) any32 = 0;
  __syncthreads();
  int t = threadIdx.x;
  long long idx = (long long)t * (E / 256);
  if (idx < E) {
    if (u[2 * idx + 1] != 0u) any32 = 1;  // race-benign: all writers store 1
  }
  __syncthreads();
  if (threadIdx.x == 0) flag[0] = any32 ? 0 : 1;  // 1 => int64
}

__global__ void conv_edges_kernel(const void* __restrict__ ei,
                                  int* __restrict__ rows, int* __restrict__ cols,
                                  int E, const int* __restrict__ flag) {
  int is64 = flag[0];
  for (int e = blockIdx.x * blockDim.x + threadIdx.x; e < E;
       e += gridDim.x * blockDim.x) {
    int r, c;
    if (is64) {
      const long long* p = (const long long*)ei;
      r = (int)p[e];
      c = (int)p[(size_t)E + e];
    } else {
      const int* p = (const int*)ei;
      r = p[e];
      c = p[(size_t)E + e];
    }
    rows[e] = r;
    cols[e] = c;
  }
}

// ---------------------------------------------------------------- degree / norm
__global__ void hist_kernel(const int* __restrict__ cols, int* __restrict__ cnt,
                            int E) {
  for (int e = blockIdx.x * blockDim.x + threadIdx.x; e < E;
       e += gridDim.x * blockDim.x) {
    atomicAdd(&cnt[cols[e]], 1);
  }
}

__global__ void dis_kernel(const int* __restrict__ cnt, float* __restrict__ dis,
                           int n) {
  int i = blockIdx.x * blockDim.x + threadIdx.x;
  if (i < n) {
    // deg includes the self loop -> always >= 1, no zero guard needed
    dis[i] = rsqrtf((float)(cnt[i] + 1));
  }
}

// ---------------------------------------------------------------- exclusive scan (3 phases)
__global__ void scan1_kernel(const int* __restrict__ cnt, int* __restrict__ off,
                             int* __restrict__ bsums, int n) {
  __shared__ int s[256];
  int t = threadIdx.x;
  int i = blockIdx.x * 256 + t;
  int v = (i < n) ? cnt[i] : 0;
  s[t] = v;
  __syncthreads();
  for (int d = 1; d < 256; d <<= 1) {
    int add = (t >= d) ? s[t - d] : 0;
    __syncthreads();
    s[t] += add;
    __syncthreads();
  }
  if (i < n) off[i] = s[t] - v;  // exclusive within chunk
  if (t == 255) bsums[blockIdx.x] = s[255];
}

__global__ void scan2_kernel(int* __restrict__ bsums, int G) {
  __shared__ int s[256];
  int t = threadIdx.x;
  int carry = 0;
  for (int base = 0; base < G; base += 256) {
    int i = base + t;
    int v = (i < G) ? bsums[i] : 0;
    s[t] = v;
    __syncthreads();
    for (int d = 1; d < 256; d <<= 1) {
      int add = (t >= d) ? s[t - d] : 0;
      __syncthreads();
      s[t] += add;
      __syncthreads();
    }
    if (i < G) bsums[i] = carry + s[t] - v;  // exclusive block offsets
    int tot = s[255];
    __syncthreads();
    carry += tot;
  }
}

__global__ void scan3_kernel(int* __restrict__ off, const int* __restrict__ bsums,
                             int n) {
  int i = blockIdx.x * blockDim.x + threadIdx.x;
  if (i < n) off[i] += bsums[i >> 8];
}

// ---------------------------------------------------------------- CSR scatter
__global__ void scatter_kernel(const int* __restrict__ rows,
                               const int* __restrict__ cols,
                               const float* __restrict__ dis,
                               const int* __restrict__ off,
                               int* __restrict__ cursor,
                               int2* __restrict__ sorted, int E) {
  for (int e = blockIdx.x * blockDim.x + threadIdx.x; e < E;
       e += gridDim.x * blockDim.x) {
    int r = rows[e];
    int c = cols[e];
    int pos = off[c] + atomicAdd(&cursor[c], 1);
    float nrm = dis[r] * dis[c];
    sorted[pos] = make_int2(r, __float_as_int(nrm));
  }
}

// ---------------------------------------------------------------- fp32 GEMM: C[n x 128] = A[n x 128] @ W[128 x 128]
// 32 rows per block, 256 threads; thread computes 4 rows x 4 cols.
__global__ __launch_bounds__(256) void gemm128_kernel(
    const float* __restrict__ A, const float* __restrict__ W,
    float* __restrict__ C, int n) {
  __shared__ float Ws[DF * DF];    // 64 KB
  __shared__ float As[32 * DF];    // 16 KB
  int tid = threadIdx.x;
  int row0 = blockIdx.x * 32;

  // stage W: 4096 float4 / 256 threads = 16 each
  const float4* W4 = (const float4*)W;
  float4* Ws4 = (float4*)Ws;
#pragma unroll
  for (int it = 0; it < 16; ++it) Ws4[it * 256 + tid] = W4[it * 256 + tid];

  // stage A tile: 1024 float4 / 256 threads = 4 each
  const float4* A4 = (const float4*)A;
  float4* As4 = (float4*)As;
#pragma unroll
  for (int it = 0; it < 4; ++it) {
    int fi = it * 256 + tid;
    int rl = fi >> 5;        // local row
    int c4 = fi & 31;        // float4 col
    int gr = row0 + rl;
    float4 v = make_float4(0.f, 0.f, 0.f, 0.f);
    if (gr < n) v = A4[(size_t)gr * 32 + c4];
    As4[fi] = v;
  }
  __syncthreads();

  int c0 = (tid & 31) * 4;        // output col base
  int r0 = (tid >> 5) * 4;        // local output row base

  float4 acc[4];
#pragma unroll
  for (int i = 0; i < 4; ++i) acc[i] = make_float4(0.f, 0.f, 0.f, 0.f);

#pragma unroll
  for (int k = 0; k < DF; k += 4) {
    float4 w0 = *(const float4*)&Ws[(k + 0) * DF + c0];
    float4 w1 = *(const float4*)&Ws[(k + 1) * DF + c0];
    float4 w2 = *(const float4*)&Ws[(k + 2) * DF + c0];
    float4 w3 = *(const float4*)&Ws[(k + 3) * DF + c0];
#pragma unroll
    for (int i = 0; i < 4; ++i) {
      float4 a = *(const float4*)&As[(r0 + i) * DF + k];
      acc[i].x += a.x * w0.x + a.y * w1.x + a.z * w2.x + a.w * w3.x;
      acc[i].y += a.x * w0.y + a.y * w1.y + a.z * w2.y + a.w * w3.y;
      acc[i].z += a.x * w0.z + a.y * w1.z + a.z * w2.z + a.w * w3.z;
      acc[i].w += a.x * w0.w + a.y * w1.w + a.z * w2.w + a.w * w3.w;
    }
  }

#pragma unroll
  for (int i = 0; i < 4; ++i) {
    int gr = row0 + r0 + i;
    if (gr < n) *(float4*)&C[(size_t)gr * DF + c0] = acc[i];
  }
}

// ---------------------------------------------------------------- aggregation: one wave per node
__global__ __launch_bounds__(256) void agg_kernel(
    const float* __restrict__ h, const int2* __restrict__ se,
    const int* __restrict__ off, const int* __restrict__ cnt,
    const float* __restrict__ dis, const float* __restrict__ bias,
    float* __restrict__ out, int n, int relu) {
  int wid = (blockIdx.x * blockDim.x + threadIdx.x) >> 6;
  int lane = threadIdx.x & 63;
  if (wid >= n) return;

  float di = dis[wid];
  float sn = di * di;  // self-loop norm
  const float2* hp = (const float2*)(h + (size_t)wid * DF);
  float2 v = hp[lane];
  float ax = v.x * sn, ay = v.y * sn;

  int s = off[wid];
  int e = s + cnt[wid];
  for (int j = s; j < e; ++j) {
    int2 ed = se[j];
    float nrm = __int_as_float(ed.y);
    const float2* sp = (const float2*)(h + (size_t)ed.x * DF);
    float2 sv = sp[lane];
    ax += sv.x * nrm;
    ay += sv.y * nrm;
  }

  float2 bb = ((const float2*)bias)[lane];
  ax += bb.x;
  ay += bb.y;
  if (relu) {
    ax = lrelu(ax);
    ay = lrelu(ay);
  }
  float2 r;
  r.x = ax;
  r.y = ay;
  ((float2*)(out + (size_t)wid * DF))[lane] = r;
}

// ---------------------------------------------------------------- launch
extern "C" void kernel_launch(void* const* d_in, const int* in_sizes, int n_in,
                              void* d_out, int out_size, void* d_ws, size_t ws_size,
                              hipStream_t stream) {
  const float* x  = (const float*)d_in[0];
  const void*  ei = d_in[1];
  const float* W1 = (const float*)d_in[2];
  const float* b1 = (const float*)d_in[3];
  const float* W2 = (const float*)d_in[4];
  const float* b2 = (const float*)d_in[5];
  float* out = (float*)d_out;

  int n = in_sizes[0] / DF;  // 50000
  int E = in_sizes[1] / 2;   // 800000

  // workspace carve (16B aligned)
  char* w = (char*)d_ws;
  auto carve = [&](size_t bytes) {
    char* p = w;
    w += (bytes + 15) & ~(size_t)15;
    return p;
  };
  float* dis    = (float*)carve((size_t)n * 4);
  int*   cnt    = (int*)carve((size_t)n * 4);
  int*   off    = (int*)carve((size_t)n * 4);
  int*   cursor = (int*)carve((size_t)n * 4);
  int*   bsums  = (int*)carve(4096);
  int*   flag   = (int*)carve(16);
  int*   rows   = (int*)carve((size_t)E * 4);
  int*   cols   = (int*)carve((size_t)E * 4);
  int2*  sorted = (int2*)carve((size_t)E * 8);
  float* bufA   = (float*)carve((size_t)n * DF * 4);

  int gE = (E + 255) / 256;    // 3125
  int gN = (n + 255) / 256;    // 196
  int G  = gN;                 // scan blocks

  hipMemsetAsync(cnt, 0, (size_t)n * 4, stream);
  hipMemsetAsync(cursor, 0, (size_t)n * 4, stream);

  detect64_kernel<<<1, 256, 0, stream>>>((const unsigned int*)ei, E, flag);
  conv_edges_kernel<<<gE, 256, 0, stream>>>(ei, rows, cols, E, flag);
  hist_kernel<<<gE, 256, 0, stream>>>(cols, cnt, E);
  dis_kernel<<<gN, 256, 0, stream>>>(cnt, dis, n);
  scan1_kernel<<<G, 256, 0, stream>>>(cnt, off, bsums, n);
  scan2_kernel<<<1, 256, 0, stream>>>(bsums, G);
  scan3_kernel<<<gN, 256, 0, stream>>>(off, bsums, n);
  scatter_kernel<<<gE, 256, 0, stream>>>(rows, cols, dis, off, cursor, sorted, E);

  int gGemm = (n + 31) / 32;       // 1563
  int gAgg  = (n + 3) / 4;         // 12500 (4 waves/block)

  // layer 1: h1 = x @ W1 ; out_tmp = agg(h1) + b1
  gemm128_kernel<<<gGemm, 256, 0, stream>>>(x, W1, bufA, n);
  agg_kernel<<<gAgg, 256, 0, stream>>>(bufA, sorted, off, cnt, dis, b1, out, n, 0);

  // layer 2: h2 = out_tmp @ W2 ; out = lrelu(agg(h2) + b2)
  gemm128_kernel<<<gGemm, 256, 0, stream>>>(out, W2, bufA, n);
  agg_kernel<<<gAgg, 256, 0, stream>>>(bufA, sorted, off, cnt, dis, b2, out, n, 1);
}

// Round 2
// 350.535 us; speedup vs baseline: 3.7194x; 3.7194x over previous
//
#include <hip/hip_runtime.h>

#define DF 128  // feature dim

// ---------------------------------------------------------------- utilities
static __device__ __forceinline__ float lrelu(float x) {
  return x > 0.f ? x : 0.1f * x;
}

// Detect whether edge_index buffer is int64 (odd 32-bit words all zero) or int32.
__global__ void detect64_kernel(const unsigned int* __restrict__ u, int E,
                                int* __restrict__ flag) {
  __shared__ int any32;
  if (threadIdx.x == 0) any32 = 0;
  __syncthreads();
  int t = threadIdx.x;
  long long idx = (long long)t * (E / 256);
  if (idx < E) {
    if (u[2 * idx + 1] != 0u) any32 = 1;  // race-benign: all writers store 1
  }
  __syncthreads();
  if (threadIdx.x == 0) flag[0] = any32 ? 0 : 1;  // 1 => int64
}

__global__ void conv_edges_kernel(const void* __restrict__ ei,
                                  int* __restrict__ rows, int* __restrict__ cols,
                                  int E, const int* __restrict__ flag) {
  int is64 = flag[0];
  for (int e = blockIdx.x * blockDim.x + threadIdx.x; e < E;
       e += gridDim.x * blockDim.x) {
    int r, c;
    if (is64) {
      const long long* p = (const long long*)ei;
      r = (int)p[e];
      c = (int)p[(size_t)E + e];
    } else {
      const int* p = (const int*)ei;
      r = p[e];
      c = p[(size_t)E + e];
    }
    rows[e] = r;
    cols[e] = c;
  }
}

// ---------------------------------------------------------------- degree / norm
__global__ void hist_kernel(const int* __restrict__ cols, int* __restrict__ cnt,
                            int E) {
  for (int e = blockIdx.x * blockDim.x + threadIdx.x; e < E;
       e += gridDim.x * blockDim.x) {
    atomicAdd(&cnt[cols[e]], 1);
  }
}

__global__ void dis_kernel(const int* __restrict__ cnt, float* __restrict__ dis,
                           int n) {
  int i = blockIdx.x * blockDim.x + threadIdx.x;
  if (i < n) {
    // deg includes the self loop -> always >= 1, no zero guard needed
    dis[i] = rsqrtf((float)(cnt[i] + 1));
  }
}

// ---------------------------------------------------------------- exclusive scan (3 phases)
__global__ void scan1_kernel(const int* __restrict__ cnt, int* __restrict__ off,
                             int* __restrict__ bsums, int n) {
  __shared__ int s[256];
  int t = threadIdx.x;
  int i = blockIdx.x * 256 + t;
  int v = (i < n) ? cnt[i] : 0;
  s[t] = v;
  __syncthreads();
  for (int d = 1; d < 256; d <<= 1) {
    int add = (t >= d) ? s[t - d] : 0;
    __syncthreads();
    s[t] += add;
    __syncthreads();
  }
  if (i < n) off[i] = s[t] - v;  // exclusive within chunk
  if (t == 255) bsums[blockIdx.x] = s[255];
}

__global__ void scan2_kernel(int* __restrict__ bsums, int G) {
  __shared__ int s[256];
  int t = threadIdx.x;
  int carry = 0;
  for (int base = 0; base < G; base += 256) {
    int i = base + t;
    int v = (i < G) ? bsums[i] : 0;
    s[t] = v;
    __syncthreads();
    for (int d = 1; d < 256; d <<= 1) {
      int add = (t >= d) ? s[t - d] : 0;
      __syncthreads();
      s[t] += add;
      __syncthreads();
    }
    if (i < G) bsums[i] = carry + s[t] - v;  // exclusive block offsets
    int tot = s[255];
    __syncthreads();
    carry += tot;
  }
}

__global__ void scan3_kernel(int* __restrict__ off, const int* __restrict__ bsums,
                             int n) {
  int i = blockIdx.x * blockDim.x + threadIdx.x;
  if (i < n) off[i] += bsums[i >> 8];
}

// ---------------------------------------------------------------- CSR scatter
__global__ void scatter_kernel(const int* __restrict__ rows,
                               const int* __restrict__ cols,
                               const float* __restrict__ dis,
                               const int* __restrict__ off,
                               int* __restrict__ cursor,
                               int2* __restrict__ sorted, int E) {
  for (int e = blockIdx.x * blockDim.x + threadIdx.x; e < E;
       e += gridDim.x * blockDim.x) {
    int r = rows[e];
    int c = cols[e];
    int pos = off[c] + atomicAdd(&cursor[c], 1);
    float nrm = dis[r] * dis[c];
    sorted[pos] = make_int2(r, __float_as_int(nrm));
  }
}

// ---------------------------------------------------------------- fp32 GEMM
// C[n x 128] = A[n x 128] @ W[128 x 128]
// Block: 256 threads, 64 rows. Thread: 8 rows x 4 cols.
// k-panel staging (KP=32): Ws 16KB + As 8KB = 24KB LDS.
// __launch_bounds__(256,4): cap VGPRs at 128 (4 waves/SIMD) -> no spill.
__global__ __launch_bounds__(256, 4) void gemm128_kernel(
    const float* __restrict__ A, const float* __restrict__ W,
    float* __restrict__ C, int n) {
  __shared__ float Ws[32 * DF];   // [k(32)][c(128)] 16 KB
  __shared__ float As[64 * 32];   // [row(64)][k(32)] 8 KB
  int tid = threadIdx.x;
  int row0 = blockIdx.x * 64;

  int c0 = (tid & 31) * 4;        // output col base (0..124)
  int r0 = (tid >> 5) * 8;        // local output row base (0..56)

  float4 acc[8];
#pragma unroll
  for (int i = 0; i < 8; ++i) acc[i] = make_float4(0.f, 0.f, 0.f, 0.f);

  const float4* A4 = (const float4*)A;
  const float4* W4 = (const float4*)W;
  float4* Ws4 = (float4*)Ws;
  float4* As4 = (float4*)As;

  for (int kp = 0; kp < 4; ++kp) {
    __syncthreads();  // protect previous panel's readers
    // stage W panel: 32 k x 128 c = 1024 float4 / 256 thr = 4 each
#pragma unroll
    for (int it = 0; it < 4; ++it) {
      int fi = it * 256 + tid;
      int k = fi >> 5;          // 0..31
      int c4 = fi & 31;         // float4 col
      Ws4[fi] = W4[(size_t)(kp * 32 + k) * 32 + c4];
    }
    // stage A panel: 64 rows x 32 k = 512 float4 / 256 thr = 2 each
#pragma unroll
    for (int it = 0; it < 2; ++it) {
      int fi = it * 256 + tid;
      int rl = fi >> 3;         // 0..63
      int c4 = fi & 7;          // float4 within panel row
      int gr = row0 + rl;
      float4 v = make_float4(0.f, 0.f, 0.f, 0.f);
      if (gr < n) v = A4[(size_t)gr * 32 + kp * 8 + c4];
      As4[fi] = v;
    }
    __syncthreads();

#pragma unroll 2
    for (int k = 0; k < 32; k += 4) {
      float4 w0 = *(const float4*)&Ws[(k + 0) * DF + c0];
      float4 w1 = *(const float4*)&Ws[(k + 1) * DF + c0];
      float4 w2 = *(const float4*)&Ws[(k + 2) * DF + c0];
      float4 w3 = *(const float4*)&Ws[(k + 3) * DF + c0];
#pragma unroll
      for (int i = 0; i < 8; ++i) {
        float4 a = *(const float4*)&As[(r0 + i) * 32 + k];
        acc[i].x += a.x * w0.x + a.y * w1.x + a.z * w2.x + a.w * w3.x;
        acc[i].y += a.x * w0.y + a.y * w1.y + a.z * w2.y + a.w * w3.y;
        acc[i].z += a.x * w0.z + a.y * w1.z + a.z * w2.z + a.w * w3.z;
        acc[i].w += a.x * w0.w + a.y * w1.w + a.z * w2.w + a.w * w3.w;
      }
    }
  }

#pragma unroll
  for (int i = 0; i < 8; ++i) {
    int gr = row0 + r0 + i;
    if (gr < n) *(float4*)&C[(size_t)gr * DF + c0] = acc[i];
  }
}

// ---------------------------------------------------------------- aggregation: one wave per node
__global__ __launch_bounds__(256) void agg_kernel(
    const float* __restrict__ h, const int2* __restrict__ se,
    const int* __restrict__ off, const int* __restrict__ cnt,
    const float* __restrict__ dis, const float* __restrict__ bias,
    float* __restrict__ out, int n, int relu) {
  int wid = (blockIdx.x * blockDim.x + threadIdx.x) >> 6;
  int lane = threadIdx.x & 63;
  if (wid >= n) return;

  float di = dis[wid];
  float sn = di * di;  // self-loop norm
  const float2* hp = (const float2*)(h + (size_t)wid * DF);
  float2 v = hp[lane];
  float ax = v.x * sn, ay = v.y * sn;

  int s = off[wid];
  int e = s + cnt[wid];
  for (int j = s; j < e; ++j) {
    int2 ed = se[j];
    float nrm = __int_as_float(ed.y);
    const float2* sp = (const float2*)(h + (size_t)ed.x * DF);
    float2 sv = sp[lane];
    ax += sv.x * nrm;
    ay += sv.y * nrm;
  }

  float2 bb = ((const float2*)bias)[lane];
  ax += bb.x;
  ay += bb.y;
  if (relu) {
    ax = lrelu(ax);
    ay = lrelu(ay);
  }
  float2 r;
  r.x = ax;
  r.y = ay;
  ((float2*)(out + (size_t)wid * DF))[lane] = r;
}

// ---------------------------------------------------------------- launch
extern "C" void kernel_launch(void* const* d_in, const int* in_sizes, int n_in,
                              void* d_out, int out_size, void* d_ws, size_t ws_size,
                              hipStream_t stream) {
  const float* x  = (const float*)d_in[0];
  const void*  ei = d_in[1];
  const float* W1 = (const float*)d_in[2];
  const float* b1 = (const float*)d_in[3];
  const float* W2 = (const float*)d_in[4];
  const float* b2 = (const float*)d_in[5];
  float* out = (float*)d_out;

  int n = in_sizes[0] / DF;  // 50000
  int E = in_sizes[1] / 2;   // 800000

  // workspace carve (16B aligned)
  char* w = (char*)d_ws;
  auto carve = [&](size_t bytes) {
    char* p = w;
    w += (bytes + 15) & ~(size_t)15;
    return p;
  };
  float* dis    = (float*)carve((size_t)n * 4);
  int*   cnt    = (int*)carve((size_t)n * 4);
  int*   off    = (int*)carve((size_t)n * 4);
  int*   cursor = (int*)carve((size_t)n * 4);
  int*   bsums  = (int*)carve(4096);
  int*   flag   = (int*)carve(16);
  int*   rows   = (int*)carve((size_t)E * 4);
  int*   cols   = (int*)carve((size_t)E * 4);
  int2*  sorted = (int2*)carve((size_t)E * 8);
  float* bufA   = (float*)carve((size_t)n * DF * 4);

  int gE = (E + 255) / 256;    // 3125
  int gN = (n + 255) / 256;    // 196
  int G  = gN;                 // scan blocks

  hipMemsetAsync(cnt, 0, (size_t)n * 4, stream);
  hipMemsetAsync(cursor, 0, (size_t)n * 4, stream);

  detect64_kernel<<<1, 256, 0, stream>>>((const unsigned int*)ei, E, flag);
  conv_edges_kernel<<<gE, 256, 0, stream>>>(ei, rows, cols, E, flag);
  hist_kernel<<<gE, 256, 0, stream>>>(cols, cnt, E);
  dis_kernel<<<gN, 256, 0, stream>>>(cnt, dis, n);
  scan1_kernel<<<G, 256, 0, stream>>>(cnt, off, bsums, n);
  scan2_kernel<<<1, 256, 0, stream>>>(bsums, G);
  scan3_kernel<<<gN, 256, 0, stream>>>(off, bsums, n);
  scatter_kernel<<<gE, 256, 0, stream>>>(rows, cols, dis, off, cursor, sorted, E);

  int gGemm = (n + 63) / 64;       // 782
  int gAgg  = (n + 3) / 4;         // 12500 (4 waves/block)

  // layer 1: h1 = x @ W1 ; out_tmp = agg(h1) + b1
  gemm128_kernel<<<gGemm, 256, 0, stream>>>(x, W1, bufA, n);
  agg_kernel<<<gAgg, 256, 0, stream>>>(bufA, sorted, off, cnt, dis, b1, out, n, 0);

  // layer 2: h2 = out_tmp @ W2 ; out = lrelu(agg(h2) + b2)
  gemm128_kernel<<<gGemm, 256, 0, stream>>>(out, W2, bufA, n);
  agg_kernel<<<gAgg, 256, 0, stream>>>(bufA, sorted, off, cnt, dis, b2, out, n, 1);
}

// Round 3
// 246.372 us; speedup vs baseline: 5.2919x; 1.4228x over previous
//
#include <hip/hip_runtime.h>

#define DF 128  // feature dim

// ---------------------------------------------------------------- utilities
static __device__ __forceinline__ float lrelu(float x) {
  return x > 0.f ? x : 0.1f * x;
}

// fp32 -> bf16 round-to-nearest-even
static __device__ __forceinline__ unsigned short f2bf(float f) {
  unsigned int u = __float_as_uint(f);
  u += 0x7FFFu + ((u >> 16) & 1u);
  return (unsigned short)(u >> 16);
}

// Detect whether edge_index buffer is int64 (odd 32-bit words all zero) or int32.
__global__ void detect64_kernel(const unsigned int* __restrict__ u, int E,
                                int* __restrict__ flag) {
  __shared__ int any32;
  if (threadIdx.x == 0) any32 = 0;
  __syncthreads();
  int t = threadIdx.x;
  long long idx = (long long)t * (E / 256);
  if (idx < E) {
    if (u[2 * idx + 1] != 0u) any32 = 1;  // race-benign: all writers store 1
  }
  __syncthreads();
  if (threadIdx.x == 0) flag[0] = any32 ? 0 : 1;  // 1 => int64
}

// convert edges to int32 rows/cols AND histogram targets in one pass
__global__ void conv_hist_kernel(const void* __restrict__ ei,
                                 int* __restrict__ rows, int* __restrict__ cols,
                                 int* __restrict__ cnt, int E,
                                 const int* __restrict__ flag) {
  int is64 = flag[0];
  for (int e = blockIdx.x * blockDim.x + threadIdx.x; e < E;
       e += gridDim.x * blockDim.x) {
    int r, c;
    if (is64) {
      const long long* p = (const long long*)ei;
      r = (int)p[e];
      c = (int)p[(size_t)E + e];
    } else {
      const int* p = (const int*)ei;
      r = p[e];
      c = p[(size_t)E + e];
    }
    rows[e] = r;
    cols[e] = c;
    atomicAdd(&cnt[c], 1);
  }
}

// ---------------------------------------------------------------- degree / norm
__global__ void dis_kernel(const int* __restrict__ cnt, float* __restrict__ dis,
                           int n) {
  int i = blockIdx.x * blockDim.x + threadIdx.x;
  if (i < n) {
    // deg includes the self loop -> always >= 1, no zero guard needed
    dis[i] = rsqrtf((float)(cnt[i] + 1));
  }
}

// ---------------------------------------------------------------- exclusive scan (3 phases)
__global__ void scan1_kernel(const int* __restrict__ cnt, int* __restrict__ off,
                             int* __restrict__ bsums, int n) {
  __shared__ int s[256];
  int t = threadIdx.x;
  int i = blockIdx.x * 256 + t;
  int v = (i < n) ? cnt[i] : 0;
  s[t] = v;
  __syncthreads();
  for (int d = 1; d < 256; d <<= 1) {
    int add = (t >= d) ? s[t - d] : 0;
    __syncthreads();
    s[t] += add;
    __syncthreads();
  }
  if (i < n) off[i] = s[t] - v;  // exclusive within chunk
  if (t == 255) bsums[blockIdx.x] = s[255];
}

__global__ void scan2_kernel(int* __restrict__ bsums, int G) {
  __shared__ int s[256];
  int t = threadIdx.x;
  int carry = 0;
  for (int base = 0; base < G; base += 256) {
    int i = base + t;
    int v = (i < G) ? bsums[i] : 0;
    s[t] = v;
    __syncthreads();
    for (int d = 1; d < 256; d <<= 1) {
      int add = (t >= d) ? s[t - d] : 0;
      __syncthreads();
      s[t] += add;
      __syncthreads();
    }
    if (i < G) bsums[i] = carry + s[t] - v;  // exclusive block offsets
    int tot = s[255];
    __syncthreads();
    carry += tot;
  }
}

__global__ void scan3_kernel(int* __restrict__ off, const int* __restrict__ bsums,
                             int n) {
  int i = blockIdx.x * blockDim.x + threadIdx.x;
  if (i < n) off[i] += bsums[i >> 8];
}

// ---------------------------------------------------------------- CSR scatter
__global__ void scatter_kernel(const int* __restrict__ rows,
                               const int* __restrict__ cols,
                               const float* __restrict__ dis,
                               const int* __restrict__ off,
                               int* __restrict__ cursor,
                               int2* __restrict__ sorted, int E) {
  for (int e = blockIdx.x * blockDim.x + threadIdx.x; e < E;
       e += gridDim.x * blockDim.x) {
    int r = rows[e];
    int c = cols[e];
    int pos = off[c] + atomicAdd(&cursor[c], 1);
    float nrm = dis[r] * dis[c];
    sorted[pos] = make_int2(r, __float_as_int(nrm));
  }
}

// ---------------------------------------------------------------- fp32 GEMM -> bf16 out
// C_bf16[n x 128] = A_f32[n x 128] @ W_f32[128 x 128]
// Block: 512 threads, tile 128 rows x 128 cols. Thread: 4 rows x 8 cols
// (two 4-col blocks 64 apart). As transposed [k][row] with +1 pad -> all
// LDS reads are conflict-free b128 (broadcast across 16-lane groups).
__global__ __launch_bounds__(512, 4) void gemm128_kernel(
    const float* __restrict__ A, const float* __restrict__ W,
    unsigned short* __restrict__ C, int n) {
  __shared__ float Ws[32 * DF];       // [k(32)][c(128)]  16 KB
  __shared__ float As[32 * 129];      // [k(32)][row(128+pad)] 16.5 KB
  int tid = threadIdx.x;
  int row0 = blockIdx.x * 128;

  int cg = tid & 15;        // col group 0..15
  int rg = tid >> 4;        // row group 0..31
  int c0 = cg * 4;          // cols {c0..c0+3, c0+64..c0+67}
  int r0 = rg * 4;          // rows r0..r0+3

  float4 acc0[4], acc1[4];
#pragma unroll
  for (int i = 0; i < 4; ++i) {
    acc0[i] = make_float4(0.f, 0.f, 0.f, 0.f);
    acc1[i] = make_float4(0.f, 0.f, 0.f, 0.f);
  }

  const float4* A4 = (const float4*)A;
  const float4* W4 = (const float4*)W;
  float4* Ws4 = (float4*)Ws;

  for (int kp = 0; kp < 4; ++kp) {
    __syncthreads();  // protect previous panel's readers
    // stage W panel: 32k x 128c = 1024 float4 / 512 thr = 2 each
#pragma unroll
    for (int it = 0; it < 2; ++it) {
      int fi = it * 512 + tid;
      int k = fi >> 5;          // 0..31
      int c4 = fi & 31;         // float4 col
      Ws4[fi] = W4[(size_t)(kp * 32 + k) * 32 + c4];
    }
    // stage A panel transposed: 128 rows x 8 float4 = 1024 / 512 thr = 2 each
#pragma unroll
    for (int it = 0; it < 2; ++it) {
      int fi = it * 512 + tid;
      int rl = fi >> 3;         // 0..127
      int c4 = fi & 7;          // float4 within 32-k panel
      int gr = row0 + rl;
      float4 v = make_float4(0.f, 0.f, 0.f, 0.f);
      if (gr < n) v = A4[(size_t)gr * 32 + kp * 8 + c4];
      As[(c4 * 4 + 0) * 129 + rl] = v.x;
      As[(c4 * 4 + 1) * 129 + rl] = v.y;
      As[(c4 * 4 + 2) * 129 + rl] = v.z;
      As[(c4 * 4 + 3) * 129 + rl] = v.w;
    }
    __syncthreads();

#pragma unroll 8
    for (int k = 0; k < 32; ++k) {
      float4 a  = *(const float4*)&As[k * 129 + r0];
      float4 b0 = *(const float4*)&Ws[k * DF + c0];
      float4 b1 = *(const float4*)&Ws[k * DF + c0 + 64];
#pragma unroll
      for (int i = 0; i < 4; ++i) {
        float av = (&a.x)[i];
        acc0[i].x += av * b0.x; acc0[i].y += av * b0.y;
        acc0[i].z += av * b0.z; acc0[i].w += av * b0.w;
        acc1[i].x += av * b1.x; acc1[i].y += av * b1.y;
        acc1[i].z += av * b1.z; acc1[i].w += av * b1.w;
      }
    }
  }

#pragma unroll
  for (int i = 0; i < 4; ++i) {
    int gr = row0 + r0 + i;
    if (gr < n) {
      ushort4 p0, p1;
      p0.x = f2bf(acc0[i].x); p0.y = f2bf(acc0[i].y);
      p0.z = f2bf(acc0[i].z); p0.w = f2bf(acc0[i].w);
      p1.x = f2bf(acc1[i].x); p1.y = f2bf(acc1[i].y);
      p1.z = f2bf(acc1[i].z); p1.w = f2bf(acc1[i].w);
      *(ushort4*)&C[(size_t)gr * DF + c0] = p0;
      *(ushort4*)&C[(size_t)gr * DF + c0 + 64] = p1;
    }
  }
}

// ---------------------------------------------------------------- aggregation: one wave per node
// h is bf16 (256 B/row); each lane holds 2 columns; accumulate fp32.
__global__ __launch_bounds__(256) void agg_kernel(
    const unsigned short* __restrict__ h, const int2* __restrict__ se,
    const int* __restrict__ off, const int* __restrict__ cnt,
    const float* __restrict__ dis, const float* __restrict__ bias,
    float* __restrict__ out, int n, int relu) {
  int wid = (blockIdx.x * blockDim.x + threadIdx.x) >> 6;
  int lane = threadIdx.x & 63;
  if (wid >= n) return;

  float di = dis[wid];
  float sn = di * di;  // self-loop norm
  unsigned int us = ((const unsigned int*)(h + (size_t)wid * DF))[lane];
  float ax = __uint_as_float(us << 16) * sn;
  float ay = __uint_as_float(us & 0xFFFF0000u) * sn;

  int s = off[wid];
  int e = s + cnt[wid];
  int j = s;
  int e4 = s + ((e - s) & ~3);
  for (; j < e4; j += 4) {
    int2 d0 = se[j + 0];
    int2 d1 = se[j + 1];
    int2 d2 = se[j + 2];
    int2 d3 = se[j + 3];
    unsigned int u0 = ((const unsigned int*)(h + (size_t)d0.x * DF))[lane];
    unsigned int u1 = ((const unsigned int*)(h + (size_t)d1.x * DF))[lane];
    unsigned int u2 = ((const unsigned int*)(h + (size_t)d2.x * DF))[lane];
    unsigned int u3 = ((const unsigned int*)(h + (size_t)d3.x * DF))[lane];
    float n0 = __int_as_float(d0.y), n1 = __int_as_float(d1.y);
    float n2 = __int_as_float(d2.y), n3 = __int_as_float(d3.y);
    ax = fmaf(__uint_as_float(u0 << 16), n0, ax);
    ay = fmaf(__uint_as_float(u0 & 0xFFFF0000u), n0, ay);
    ax = fmaf(__uint_as_float(u1 << 16), n1, ax);
    ay = fmaf(__uint_as_float(u1 & 0xFFFF0000u), n1, ay);
    ax = fmaf(__uint_as_float(u2 << 16), n2, ax);
    ay = fmaf(__uint_as_float(u2 & 0xFFFF0000u), n2, ay);
    ax = fmaf(__uint_as_float(u3 << 16), n3, ax);
    ay = fmaf(__uint_as_float(u3 & 0xFFFF0000u), n3, ay);
  }
  for (; j < e; ++j) {
    int2 ed = se[j];
    float nrm = __int_as_float(ed.y);
    unsigned int u = ((const unsigned int*)(h + (size_t)ed.x * DF))[lane];
    ax = fmaf(__uint_as_float(u << 16), nrm, ax);
    ay = fmaf(__uint_as_float(u & 0xFFFF0000u), nrm, ay);
  }

  float2 bb = ((const float2*)bias)[lane];
  ax += bb.x;
  ay += bb.y;
  if (relu) {
    ax = lrelu(ax);
    ay = lrelu(ay);
  }
  float2 r;
  r.x = ax;
  r.y = ay;
  ((float2*)(out + (size_t)wid * DF))[lane] = r;
}

// ---------------------------------------------------------------- launch
extern "C" void kernel_launch(void* const* d_in, const int* in_sizes, int n_in,
                              void* d_out, int out_size, void* d_ws, size_t ws_size,
                              hipStream_t stream) {
  const float* x  = (const float*)d_in[0];
  const void*  ei = d_in[1];
  const float* W1 = (const float*)d_in[2];
  const float* b1 = (const float*)d_in[3];
  const float* W2 = (const float*)d_in[4];
  const float* b2 = (const float*)d_in[5];
  float* out = (float*)d_out;

  int n = in_sizes[0] / DF;  // 50000
  int E = in_sizes[1] / 2;   // 800000

  // workspace carve (16B aligned)
  char* w = (char*)d_ws;
  auto carve = [&](size_t bytes) {
    char* p = w;
    w += (bytes + 15) & ~(size_t)15;
    return p;
  };
  float* dis    = (float*)carve((size_t)n * 4);
  int*   cnt    = (int*)carve((size_t)n * 4);
  int*   off    = (int*)carve((size_t)n * 4);
  int*   cursor = (int*)carve((size_t)n * 4);
  int*   bsums  = (int*)carve(4096);
  int*   flag   = (int*)carve(16);
  int*   rows   = (int*)carve((size_t)E * 4);
  int*   cols   = (int*)carve((size_t)E * 4);
  int2*  sorted = (int2*)carve((size_t)E * 8);
  unsigned short* bufA = (unsigned short*)carve((size_t)n * DF * 2);

  int gE = (E + 255) / 256;    // 3125
  int gN = (n + 255) / 256;    // 196
  int G  = gN;                 // scan blocks

  hipMemsetAsync(cnt, 0, (size_t)n * 4, stream);
  hipMemsetAsync(cursor, 0, (size_t)n * 4, stream);

  detect64_kernel<<<1, 256, 0, stream>>>((const unsigned int*)ei, E, flag);
  conv_hist_kernel<<<gE, 256, 0, stream>>>(ei, rows, cols, cnt, E, flag);
  dis_kernel<<<gN, 256, 0, stream>>>(cnt, dis, n);
  scan1_kernel<<<G, 256, 0, stream>>>(cnt, off, bsums, n);
  scan2_kernel<<<1, 256, 0, stream>>>(bsums, G);
  scan3_kernel<<<gN, 256, 0, stream>>>(off, bsums, n);
  scatter_kernel<<<gE, 256, 0, stream>>>(rows, cols, dis, off, cursor, sorted, E);

  int gGemm = (n + 127) / 128;     // 391
  int gAgg  = (n + 3) / 4;         // 12500 (4 waves/block)

  // layer 1: h1 = bf16(x @ W1) ; out = agg(h1) + b1   (fp32)
  gemm128_kernel<<<gGemm, 512, 0, stream>>>(x, W1, bufA, n);
  agg_kernel<<<gAgg, 256, 0, stream>>>(bufA, sorted, off, cnt, dis, b1, out, n, 0);

  // layer 2: h2 = bf16(out @ W2) ; out = lrelu(agg(h2) + b2)
  gemm128_kernel<<<gGemm, 512, 0, stream>>>(out, W2, bufA, n);
  agg_kernel<<<gAgg, 256, 0, stream>>>(bufA, sorted, off, cnt, dis, b2, out, n, 1);
}

// Round 4
// 237.762 us; speedup vs baseline: 5.4835x; 1.0362x over previous
//
#include <hip/hip_runtime.h>

#define DF 128  // feature dim

typedef __bf16 bf16x8 __attribute__((ext_vector_type(8)));
typedef float f32x4 __attribute__((ext_vector_type(4)));

// ---------------------------------------------------------------- utilities
static __device__ __forceinline__ float lrelu(float x) {
  return x > 0.f ? x : 0.1f * x;
}

// fp32 -> bf16 round-to-nearest-even (bits)
static __device__ __forceinline__ unsigned short f2bf(float f) {
  unsigned int u = __float_as_uint(f);
  u += 0x7FFFu + ((u >> 16) & 1u);
  return (unsigned short)(u >> 16);
}
static __device__ __forceinline__ float bf2f(unsigned short h) {
  return __uint_as_float((unsigned int)h << 16);
}

// Detect whether edge_index buffer is int64 (odd 32-bit words all zero) or int32.
__global__ void detect64_kernel(const unsigned int* __restrict__ u, int E,
                                int* __restrict__ flag) {
  __shared__ int any32;
  if (threadIdx.x == 0) any32 = 0;
  __syncthreads();
  int t = threadIdx.x;
  long long idx = (long long)t * (E / 256);
  if (idx < E) {
    if (u[2 * idx + 1] != 0u) any32 = 1;  // race-benign: all writers store 1
  }
  __syncthreads();
  if (threadIdx.x == 0) flag[0] = any32 ? 0 : 1;  // 1 => int64
}

// convert edges to int32 rows/cols AND histogram targets in one pass
__global__ void conv_hist_kernel(const void* __restrict__ ei,
                                 int* __restrict__ rows, int* __restrict__ cols,
                                 int* __restrict__ cnt, int E,
                                 const int* __restrict__ flag) {
  int is64 = flag[0];
  for (int e = blockIdx.x * blockDim.x + threadIdx.x; e < E;
       e += gridDim.x * blockDim.x) {
    int r, c;
    if (is64) {
      const long long* p = (const long long*)ei;
      r = (int)p[e];
      c = (int)p[(size_t)E + e];
    } else {
      const int* p = (const int*)ei;
      r = p[e];
      c = p[(size_t)E + e];
    }
    rows[e] = r;
    cols[e] = c;
    atomicAdd(&cnt[c], 1);
  }
}

// ---------------------------------------------------------------- scan (3 phases), dis fused into phase 1
__global__ void scan1_kernel(const int* __restrict__ cnt, int* __restrict__ off,
                             int* __restrict__ bsums, float* __restrict__ dis,
                             int n) {
  __shared__ int s[256];
  int t = threadIdx.x;
  int i = blockIdx.x * 256 + t;
  int v = (i < n) ? cnt[i] : 0;
  if (i < n) dis[i] = rsqrtf((float)(v + 1));  // deg incl self loop >= 1
  s[t] = v;
  __syncthreads();
  for (int d = 1; d < 256; d <<= 1) {
    int add = (t >= d) ? s[t - d] : 0;
    __syncthreads();
    s[t] += add;
    __syncthreads();
  }
  if (i < n) off[i] = s[t] - v;  // exclusive within chunk
  if (t == 255) bsums[blockIdx.x] = s[255];
}

__global__ void scan2_kernel(int* __restrict__ bsums, int G) {
  __shared__ int s[256];
  int t = threadIdx.x;
  int carry = 0;
  for (int base = 0; base < G; base += 256) {
    int i = base + t;
    int v = (i < G) ? bsums[i] : 0;
    s[t] = v;
    __syncthreads();
    for (int d = 1; d < 256; d <<= 1) {
      int add = (t >= d) ? s[t - d] : 0;
      __syncthreads();
      s[t] += add;
      __syncthreads();
    }
    if (i < G) bsums[i] = carry + s[t] - v;
    int tot = s[255];
    __syncthreads();
    carry += tot;
  }
}

__global__ void scan3_kernel(int* __restrict__ off, const int* __restrict__ bsums,
                             int n) {
  int i = blockIdx.x * blockDim.x + threadIdx.x;
  if (i < n) off[i] += bsums[i >> 8];
}

// ---------------------------------------------------------------- CSR scatter
__global__ void scatter_kernel(const int* __restrict__ rows,
                               const int* __restrict__ cols,
                               const float* __restrict__ dis,
                               const int* __restrict__ off,
                               int* __restrict__ cursor,
                               int2* __restrict__ sorted, int E) {
  for (int e = blockIdx.x * blockDim.x + threadIdx.x; e < E;
       e += gridDim.x * blockDim.x) {
    int r = rows[e];
    int c = cols[e];
    int pos = off[c] + atomicAdd(&cursor[c], 1);
    float nrm = dis[r] * dis[c];
    sorted[pos] = make_int2(r, __float_as_int(nrm));
  }
}

// ---------------------------------------------------------------- W pre-split
// Split W (128x128 f32) into bf16 hi/lo stored in MFMA B-fragment-linear order:
// element W[k][c] -> frag fid = (kslab*8 + ctile)*64 + lane, pos = fid*8 + elem
// with kslab=k>>5, ctile=c>>4, lane=((k>>3)&3)*16 + (c&15), elem=k&7.
// out: [block][hi 16384][lo 16384] ushorts.
__global__ void wsplit_kernel(const float* __restrict__ W1,
                              const float* __restrict__ W2,
                              unsigned short* __restrict__ out) {
  const float* W = (blockIdx.x == 0) ? W1 : W2;
  unsigned short* hi = out + (size_t)blockIdx.x * 32768;
  unsigned short* lo = hi + 16384;
  for (int i = threadIdx.x; i < 16384; i += 256) {
    int k = i >> 7, c = i & 127;
    float w = W[i];
    unsigned short h = f2bf(w);
    unsigned short l = f2bf(w - bf2f(h));
    int fid = (((k >> 5) * 8) + (c >> 4)) * 64 + ((k >> 3) & 3) * 16 + (c & 15);
    int pos = fid * 8 + (k & 7);
    hi[pos] = h;
    lo[pos] = l;
  }
}

// ---------------------------------------------------------------- MFMA GEMM (split bf16, fp32-accurate)
// C_bf16[n x 128] = A_f32[n x 128] @ W[128 x 128]
// Block: 256 threads (4 waves), 32 rows. Wave w: row band w&1 (16 rows),
// col half w>>1 (64 cols = 4 col-tiles). 3 MFMAs per tile: hi*hi + hi*lo + lo*hi.
__global__ __launch_bounds__(256, 8) void gemm_mfma_kernel(
    const float* __restrict__ A, const unsigned short* __restrict__ wfrag,
    unsigned short* __restrict__ C, int n) {
  __shared__ unsigned short Ah[2][4][64][8];  // [band][kslab][lane][elem] 8 KB
  __shared__ unsigned short Al[2][4][64][8];  // 8 KB
  int tid = threadIdx.x;
  int row0 = blockIdx.x * 32;

  // stage A: 32 rows x 32 float4, split to bf16 hi/lo in fragment layout
  const float4* A4 = (const float4*)A;
#pragma unroll
  for (int it = 0; it < 4; ++it) {
    int fi = it * 256 + tid;
    int row = fi >> 5;          // 0..31
    int c4 = fi & 31;           // float4 index along k
    int gr = row0 + row;
    float4 v = make_float4(0.f, 0.f, 0.f, 0.f);
    if (gr < n) v = A4[(size_t)gr * 32 + c4];
    unsigned short h0 = f2bf(v.x), h1 = f2bf(v.y), h2 = f2bf(v.z), h3 = f2bf(v.w);
    unsigned short l0 = f2bf(v.x - bf2f(h0)), l1 = f2bf(v.y - bf2f(h1));
    unsigned short l2 = f2bf(v.z - bf2f(h2)), l3 = f2bf(v.w - bf2f(h3));
    int band = row >> 4;
    int kslab = c4 >> 3;
    int lane = ((c4 >> 1) & 3) * 16 + (row & 15);
    int e0 = (c4 & 1) * 4;
    *(uint2*)&Ah[band][kslab][lane][e0] =
        make_uint2((unsigned int)h0 | ((unsigned int)h1 << 16),
                   (unsigned int)h2 | ((unsigned int)h3 << 16));
    *(uint2*)&Al[band][kslab][lane][e0] =
        make_uint2((unsigned int)l0 | ((unsigned int)l1 << 16),
                   (unsigned int)l2 | ((unsigned int)l3 << 16));
  }
  __syncthreads();

  int w = tid >> 6, lane = tid & 63;
  int band = w & 1, ch = w >> 1;

  f32x4 acc[4];
#pragma unroll
  for (int t = 0; t < 4; ++t) acc[t] = (f32x4){0.f, 0.f, 0.f, 0.f};

#pragma unroll
  for (int ks = 0; ks < 4; ++ks) {
    bf16x8 ahi = *(const bf16x8*)&Ah[band][ks][lane][0];
    bf16x8 alo = *(const bf16x8*)&Al[band][ks][lane][0];
#pragma unroll
    for (int ct = 0; ct < 4; ++ct) {
      size_t fb = ((size_t)(ks * 8 + ch * 4 + ct) * 64 + lane) * 8;
      bf16x8 whi = *(const bf16x8*)&wfrag[fb];
      bf16x8 wlo = *(const bf16x8*)&wfrag[16384 + fb];
      acc[ct] = __builtin_amdgcn_mfma_f32_16x16x32_bf16(ahi, whi, acc[ct], 0, 0, 0);
      acc[ct] = __builtin_amdgcn_mfma_f32_16x16x32_bf16(ahi, wlo, acc[ct], 0, 0, 0);
      acc[ct] = __builtin_amdgcn_mfma_f32_16x16x32_bf16(alo, whi, acc[ct], 0, 0, 0);
    }
  }

  // store: C row = row0 + band*16 + (lane>>4)*4 + r, col = ch*64 + ct*16 + (lane&15)
#pragma unroll
  for (int ct = 0; ct < 4; ++ct) {
    int col = ch * 64 + ct * 16 + (lane & 15);
#pragma unroll
    for (int r = 0; r < 4; ++r) {
      int grow = row0 + band * 16 + ((lane >> 4) << 2) + r;
      if (grow < n) C[(size_t)grow * DF + col] = f2bf(acc[ct][r]);
    }
  }
}

// ---------------------------------------------------------------- aggregation: one wave per node
// h is bf16 (256 B/row); each lane holds 2 columns; fp32 accumulate; unroll 8.
__global__ __launch_bounds__(256) void agg_kernel(
    const unsigned short* __restrict__ h, const int2* __restrict__ se,
    const int* __restrict__ off, const int* __restrict__ cnt,
    const float* __restrict__ dis, const float* __restrict__ bias,
    float* __restrict__ out, int n, int relu) {
  int wid = (blockIdx.x * blockDim.x + threadIdx.x) >> 6;
  int lane = threadIdx.x & 63;
  if (wid >= n) return;

  float di = dis[wid];
  float sn = di * di;  // self-loop norm
  unsigned int us = ((const unsigned int*)(h + (size_t)wid * DF))[lane];
  float ax = __uint_as_float(us << 16) * sn;
  float ay = __uint_as_float(us & 0xFFFF0000u) * sn;

  int s = off[wid];
  int e = s + cnt[wid];
  int j = s;
  int e8 = s + ((e - s) & ~7);
  for (; j < e8; j += 8) {
    int2 d[8];
    unsigned int u[8];
#pragma unroll
    for (int q = 0; q < 8; ++q) d[q] = se[j + q];
#pragma unroll
    for (int q = 0; q < 8; ++q)
      u[q] = ((const unsigned int*)(h + (size_t)d[q].x * DF))[lane];
#pragma unroll
    for (int q = 0; q < 8; ++q) {
      float nr = __int_as_float(d[q].y);
      ax = fmaf(__uint_as_float(u[q] << 16), nr, ax);
      ay = fmaf(__uint_as_float(u[q] & 0xFFFF0000u), nr, ay);
    }
  }
  for (; j < e; ++j) {
    int2 ed = se[j];
    float nrm = __int_as_float(ed.y);
    unsigned int u = ((const unsigned int*)(h + (size_t)ed.x * DF))[lane];
    ax = fmaf(__uint_as_float(u << 16), nrm, ax);
    ay = fmaf(__uint_as_float(u & 0xFFFF0000u), nrm, ay);
  }

  float2 bb = ((const float2*)bias)[lane];
  ax += bb.x;
  ay += bb.y;
  if (relu) {
    ax = lrelu(ax);
    ay = lrelu(ay);
  }
  float2 r;
  r.x = ax;
  r.y = ay;
  ((float2*)(out + (size_t)wid * DF))[lane] = r;
}

// ---------------------------------------------------------------- launch
extern "C" void kernel_launch(void* const* d_in, const int* in_sizes, int n_in,
                              void* d_out, int out_size, void* d_ws, size_t ws_size,
                              hipStream_t stream) {
  const float* x  = (const float*)d_in[0];
  const void*  ei = d_in[1];
  const float* W1 = (const float*)d_in[2];
  const float* b1 = (const float*)d_in[3];
  const float* W2 = (const float*)d_in[4];
  const float* b2 = (const float*)d_in[5];
  float* out = (float*)d_out;

  int n = in_sizes[0] / DF;  // 50000
  int E = in_sizes[1] / 2;   // 800000

  // workspace carve (16B aligned)
  char* w = (char*)d_ws;
  auto carve = [&](size_t bytes) {
    char* p = w;
    w += (bytes + 15) & ~(size_t)15;
    return p;
  };
  float* dis    = (float*)carve((size_t)n * 4);
  int*   cnt    = (int*)carve((size_t)n * 4);   // cnt and cursor adjacent:
  int*   cursor = (int*)carve((size_t)n * 4);   // single memset covers both
  int*   off    = (int*)carve((size_t)n * 4);
  int*   bsums  = (int*)carve(4096);
  int*   flag   = (int*)carve(16);
  unsigned short* wfrag = (unsigned short*)carve(65536 * 2);  // 2 x (hi+lo) 32K shorts
  int*   rows   = (int*)carve((size_t)E * 4);
  int*   cols   = (int*)carve((size_t)E * 4);
  int2*  sorted = (int2*)carve((size_t)E * 8);
  unsigned short* bufA = (unsigned short*)carve((size_t)n * DF * 2);

  int gE = (E + 255) / 256;    // 3125
  int gN = (n + 255) / 256;    // 196
  int G  = gN;                 // scan blocks

  hipMemsetAsync(cnt, 0, (size_t)n * 8, stream);  // cnt + cursor

  wsplit_kernel<<<2, 256, 0, stream>>>(W1, W2, wfrag);
  detect64_kernel<<<1, 256, 0, stream>>>((const unsigned int*)ei, E, flag);
  conv_hist_kernel<<<gE, 256, 0, stream>>>(ei, rows, cols, cnt, E, flag);
  scan1_kernel<<<G, 256, 0, stream>>>(cnt, off, bsums, dis, n);
  scan2_kernel<<<1, 256, 0, stream>>>(bsums, G);
  scan3_kernel<<<gN, 256, 0, stream>>>(off, bsums, n);
  scatter_kernel<<<gE, 256, 0, stream>>>(rows, cols, dis, off, cursor, sorted, E);

  int gGemm = (n + 31) / 32;       // 1563
  int gAgg  = (n + 3) / 4;         // 12500 (4 waves/block)

  // layer 1: h1 = bf16(x @ W1) ; out = agg(h1) + b1   (fp32)
  gemm_mfma_kernel<<<gGemm, 256, 0, stream>>>(x, wfrag, bufA, n);
  agg_kernel<<<gAgg, 256, 0, stream>>>(bufA, sorted, off, cnt, dis, b1, out, n, 0);

  // layer 2: h2 = bf16(out @ W2) ; out = lrelu(agg(h2) + b2)
  gemm_mfma_kernel<<<gGemm, 256, 0, stream>>>(out, wfrag + 32768, bufA, n);
  agg_kernel<<<gAgg, 256, 0, stream>>>(bufA, sorted, off, cnt, dis, b2, out, n, 1);
}

// Round 5
// 227.563 us; speedup vs baseline: 5.7292x; 1.0448x over previous
//
#include <hip/hip_runtime.h>

#define DF 128  // feature dim

typedef __bf16 bf16x8 __attribute__((ext_vector_type(8)));
typedef float f32x4 __attribute__((ext_vector_type(4)));

// ---------------------------------------------------------------- utilities
static __device__ __forceinline__ float lrelu(float x) {
  return x > 0.f ? x : 0.1f * x;
}

// fp32 -> bf16 round-to-nearest-even (bits)
static __device__ __forceinline__ unsigned short f2bf(float f) {
  unsigned int u = __float_as_uint(f);
  u += 0x7FFFu + ((u >> 16) & 1u);
  return (unsigned short)(u >> 16);
}
static __device__ __forceinline__ float bf2f(unsigned short h) {
  return __uint_as_float((unsigned int)h << 16);
}

// ---------------------------------------------------------------- prep:
// blocks 0,1: split W1/W2 into bf16 hi/lo in MFMA B-fragment-linear order.
// block 2: detect int64 vs int32 edge_index.
__global__ void prep_kernel(const float* __restrict__ W1,
                            const float* __restrict__ W2,
                            unsigned short* __restrict__ wfrag,
                            const unsigned int* __restrict__ ei_u, int E,
                            int* __restrict__ flag) {
  if (blockIdx.x == 2) {
    __shared__ int any32;
    if (threadIdx.x == 0) any32 = 0;
    __syncthreads();
    long long idx = (long long)threadIdx.x * (E / 256);
    if (idx < E) {
      if (ei_u[2 * idx + 1] != 0u) any32 = 1;
    }
    __syncthreads();
    if (threadIdx.x == 0) flag[0] = any32 ? 0 : 1;  // 1 => int64
    return;
  }
  const float* W = (blockIdx.x == 0) ? W1 : W2;
  unsigned short* hi = wfrag + (size_t)blockIdx.x * 32768;
  unsigned short* lo = hi + 16384;
  for (int i = threadIdx.x; i < 16384; i += 256) {
    int k = i >> 7, c = i & 127;
    float w = W[i];
    unsigned short h = f2bf(w);
    unsigned short l = f2bf(w - bf2f(h));
    int fid = (((k >> 5) * 8) + (c >> 4)) * 64 + ((k >> 3) & 3) * 16 + (c & 15);
    int pos = fid * 8 + (k & 7);
    hi[pos] = h;
    lo[pos] = l;
  }
}

// convert edges to int32 rows/cols AND histogram targets in one pass
__global__ void conv_hist_kernel(const void* __restrict__ ei,
                                 int* __restrict__ rows, int* __restrict__ cols,
                                 int* __restrict__ cnt, int E,
                                 const int* __restrict__ flag) {
  int is64 = flag[0];
  for (int e = blockIdx.x * blockDim.x + threadIdx.x; e < E;
       e += gridDim.x * blockDim.x) {
    int r, c;
    if (is64) {
      const long long* p = (const long long*)ei;
      r = (int)p[e];
      c = (int)p[(size_t)E + e];
    } else {
      const int* p = (const int*)ei;
      r = p[e];
      c = p[(size_t)E + e];
    }
    rows[e] = r;
    cols[e] = c;
    atomicAdd(&cnt[c], 1);
  }
}

// ---------------------------------------------------------------- scan (2 kernels), dis fused
__global__ void scan1_kernel(const int* __restrict__ cnt, int* __restrict__ off,
                             int* __restrict__ bsums, float* __restrict__ dis,
                             int n) {
  __shared__ int s[256];
  int t = threadIdx.x;
  int i = blockIdx.x * 256 + t;
  int v = (i < n) ? cnt[i] : 0;
  if (i < n) dis[i] = rsqrtf((float)(v + 1));  // deg incl self loop >= 1
  s[t] = v;
  __syncthreads();
  for (int d = 1; d < 256; d <<= 1) {
    int add = (t >= d) ? s[t - d] : 0;
    __syncthreads();
    s[t] += add;
    __syncthreads();
  }
  if (i < n) off[i] = s[t] - v;  // exclusive within chunk
  if (t == 255) bsums[blockIdx.x] = s[255];
}

__global__ void scan2_kernel(int* __restrict__ bsums, int G) {
  __shared__ int s[256];
  int t = threadIdx.x;
  int carry = 0;
  for (int base = 0; base < G; base += 256) {
    int i = base + t;
    int v = (i < G) ? bsums[i] : 0;
    s[t] = v;
    __syncthreads();
    for (int d = 1; d < 256; d <<= 1) {
      int add = (t >= d) ? s[t - d] : 0;
      __syncthreads();
      s[t] += add;
      __syncthreads();
    }
    if (i < G) bsums[i] = carry + s[t] - v;
    int tot = s[255];
    __syncthreads();
    carry += tot;
  }
}

// ---------------------------------------------------------------- CSR scatter (src only; scan3 folded in)
__global__ void scatter_kernel(const int* __restrict__ rows,
                               const int* __restrict__ cols,
                               const int* __restrict__ off,
                               const int* __restrict__ bsums,
                               int* __restrict__ cursor,
                               int* __restrict__ srcs, int E) {
  for (int e = blockIdx.x * blockDim.x + threadIdx.x; e < E;
       e += gridDim.x * blockDim.x) {
    int c = cols[e];
    int pos = off[c] + bsums[c >> 8] + atomicAdd(&cursor[c], 1);
    srcs[pos] = rows[e];
  }
}

// ---------------------------------------------------------------- MFMA GEMM (split bf16, fp32-accurate)
// G_bf16[n x 128] = dis[row] * (A_f32[n x 128] @ W[128 x 128])
// Block: 256 threads (4 waves), 32 rows. Wave w: row band w&1 (16 rows),
// col half w>>1 (64 cols = 4 col-tiles). 3 MFMAs per tile: hi*hi + hi*lo + lo*hi.
__global__ __launch_bounds__(256, 8) void gemm_mfma_kernel(
    const float* __restrict__ A, const unsigned short* __restrict__ wfrag,
    const float* __restrict__ dis, unsigned short* __restrict__ G, int n) {
  __shared__ unsigned short Ah[2][4][64][8];  // [band][kslab][lane][elem] 8 KB
  __shared__ unsigned short Al[2][4][64][8];  // 8 KB
  __shared__ float disS[32];
  int tid = threadIdx.x;
  int row0 = blockIdx.x * 32;

  if (tid < 32) {
    int gr = row0 + tid;
    disS[tid] = (gr < n) ? dis[gr] : 0.f;
  }

  // stage A: 32 rows x 32 float4, split to bf16 hi/lo in fragment layout
  const float4* A4 = (const float4*)A;
#pragma unroll
  for (int it = 0; it < 4; ++it) {
    int fi = it * 256 + tid;
    int row = fi >> 5;          // 0..31
    int c4 = fi & 31;           // float4 index along k
    int gr = row0 + row;
    float4 v = make_float4(0.f, 0.f, 0.f, 0.f);
    if (gr < n) v = A4[(size_t)gr * 32 + c4];
    unsigned short h0 = f2bf(v.x), h1 = f2bf(v.y), h2 = f2bf(v.z), h3 = f2bf(v.w);
    unsigned short l0 = f2bf(v.x - bf2f(h0)), l1 = f2bf(v.y - bf2f(h1));
    unsigned short l2 = f2bf(v.z - bf2f(h2)), l3 = f2bf(v.w - bf2f(h3));
    int band = row >> 4;
    int kslab = c4 >> 3;
    int lane = ((c4 >> 1) & 3) * 16 + (row & 15);
    int e0 = (c4 & 1) * 4;
    *(uint2*)&Ah[band][kslab][lane][e0] =
        make_uint2((unsigned int)h0 | ((unsigned int)h1 << 16),
                   (unsigned int)h2 | ((unsigned int)h3 << 16));
    *(uint2*)&Al[band][kslab][lane][e0] =
        make_uint2((unsigned int)l0 | ((unsigned int)l1 << 16),
                   (unsigned int)l2 | ((unsigned int)l3 << 16));
  }
  __syncthreads();

  int w = tid >> 6, lane = tid & 63;
  int band = w & 1, ch = w >> 1;

  f32x4 acc[4];
#pragma unroll
  for (int t = 0; t < 4; ++t) acc[t] = (f32x4){0.f, 0.f, 0.f, 0.f};

#pragma unroll
  for (int ks = 0; ks < 4; ++ks) {
    bf16x8 ahi = *(const bf16x8*)&Ah[band][ks][lane][0];
    bf16x8 alo = *(const bf16x8*)&Al[band][ks][lane][0];
#pragma unroll
    for (int ct = 0; ct < 4; ++ct) {
      size_t fb = ((size_t)(ks * 8 + ch * 4 + ct) * 64 + lane) * 8;
      bf16x8 whi = *(const bf16x8*)&wfrag[fb];
      bf16x8 wlo = *(const bf16x8*)&wfrag[16384 + fb];
      acc[ct] = __builtin_amdgcn_mfma_f32_16x16x32_bf16(ahi, whi, acc[ct], 0, 0, 0);
      acc[ct] = __builtin_amdgcn_mfma_f32_16x16x32_bf16(ahi, wlo, acc[ct], 0, 0, 0);
      acc[ct] = __builtin_amdgcn_mfma_f32_16x16x32_bf16(alo, whi, acc[ct], 0, 0, 0);
    }
  }

  // store g = dis[row] * acc: row = row0+band*16+(lane>>4)*4+r, col = ch*64+ct*16+(lane&15)
#pragma unroll
  for (int ct = 0; ct < 4; ++ct) {
    int col = ch * 64 + ct * 16 + (lane & 15);
#pragma unroll
    for (int r = 0; r < 4; ++r) {
      int lrow = band * 16 + ((lane >> 4) << 2) + r;
      int grow = row0 + lrow;
      if (grow < n) G[(size_t)grow * DF + col] = f2bf(acc[ct][r] * disS[lrow]);
    }
  }
}

// ---------------------------------------------------------------- aggregation: one wave per node
// out[t] = dis[t] * (sum_{s in N(t)} g[s] + g[t]) + b ; g bf16 256 B/row.
__global__ __launch_bounds__(1024) void agg_kernel(
    const unsigned short* __restrict__ g, const int* __restrict__ srcs,
    const int* __restrict__ off, const int* __restrict__ bsums,
    const int* __restrict__ cnt, const float* __restrict__ dis,
    const float* __restrict__ bias, float* __restrict__ out, int n, int relu) {
  int wid = (blockIdx.x * blockDim.x + threadIdx.x) >> 6;
  int lane = threadIdx.x & 63;
  if (wid >= n) return;

  float diw = dis[wid];
  unsigned int us = ((const unsigned int*)(g + (size_t)wid * DF))[lane];
  float ax = __uint_as_float(us << 16);         // self term g[wid]
  float ay = __uint_as_float(us & 0xFFFF0000u);

  int s = off[wid] + bsums[wid >> 8];
  int c = cnt[wid];
  int e = s + c;
  // predicated unroll-8: clamp index to e-1, zero invalid contributions
  for (int j = s; j < e; j += 8) {
    int src[8];
    unsigned int u[8];
#pragma unroll
    for (int q = 0; q < 8; ++q) {
      int idx = j + q;
      src[q] = srcs[idx < e ? idx : e - 1];
    }
#pragma unroll
    for (int q = 0; q < 8; ++q)
      u[q] = ((const unsigned int*)(g + (size_t)src[q] * DF))[lane];
#pragma unroll
    for (int q = 0; q < 8; ++q) {
      bool v = (j + q) < e;
      float vx = __uint_as_float(u[q] << 16);
      float vy = __uint_as_float(u[q] & 0xFFFF0000u);
      ax += v ? vx : 0.f;
      ay += v ? vy : 0.f;
    }
  }

  float2 bb = ((const float2*)bias)[lane];
  ax = fmaf(ax, diw, bb.x);
  ay = fmaf(ay, diw, bb.y);
  if (relu) {
    ax = lrelu(ax);
    ay = lrelu(ay);
  }
  float2 r;
  r.x = ax;
  r.y = ay;
  ((float2*)(out + (size_t)wid * DF))[lane] = r;
}

// ---------------------------------------------------------------- launch
extern "C" void kernel_launch(void* const* d_in, const int* in_sizes, int n_in,
                              void* d_out, int out_size, void* d_ws, size_t ws_size,
                              hipStream_t stream) {
  const float* x  = (const float*)d_in[0];
  const void*  ei = d_in[1];
  const float* W1 = (const float*)d_in[2];
  const float* b1 = (const float*)d_in[3];
  const float* W2 = (const float*)d_in[4];
  const float* b2 = (const float*)d_in[5];
  float* out = (float*)d_out;

  int n = in_sizes[0] / DF;  // 50000
  int E = in_sizes[1] / 2;   // 800000

  // workspace carve (16B aligned)
  char* w = (char*)d_ws;
  auto carve = [&](size_t bytes) {
    char* p = w;
    w += (bytes + 15) & ~(size_t)15;
    return p;
  };
  float* dis    = (float*)carve((size_t)n * 4);
  int*   cnt    = (int*)carve((size_t)n * 4);   // cnt and cursor adjacent:
  int*   cursor = (int*)carve((size_t)n * 4);   // single memset covers both
  int*   off    = (int*)carve((size_t)n * 4);
  int*   bsums  = (int*)carve(4096);
  int*   flag   = (int*)carve(16);
  unsigned short* wfrag = (unsigned short*)carve(65536 * 2);  // 2 x (hi+lo)
  int*   rows   = (int*)carve((size_t)E * 4);
  int*   cols   = (int*)carve((size_t)E * 4);
  int*   srcs   = (int*)carve((size_t)E * 4);
  unsigned short* bufG = (unsigned short*)carve((size_t)n * DF * 2);

  int gE = (E + 255) / 256;    // 3125
  int gN = (n + 255) / 256;    // 196
  int G  = gN;                 // scan blocks

  hipMemsetAsync(cnt, 0, (size_t)n * 8, stream);  // cnt + cursor

  prep_kernel<<<3, 256, 0, stream>>>(W1, W2, wfrag, (const unsigned int*)ei, E, flag);
  conv_hist_kernel<<<gE, 256, 0, stream>>>(ei, rows, cols, cnt, E, flag);
  scan1_kernel<<<G, 256, 0, stream>>>(cnt, off, bsums, dis, n);
  scan2_kernel<<<1, 256, 0, stream>>>(bsums, G);
  scatter_kernel<<<gE, 256, 0, stream>>>(rows, cols, off, bsums, cursor, srcs, E);

  int gGemm = (n + 31) / 32;        // 1563
  int gAgg  = (n + 15) / 16;        // 3125 (16 waves/block)

  // layer 1: g1 = dis * bf16(x @ W1) ; out = dis*(sum g1 + g1_self) + b1
  gemm_mfma_kernel<<<gGemm, 256, 0, stream>>>(x, wfrag, dis, bufG, n);
  agg_kernel<<<gAgg, 1024, 0, stream>>>(bufG, srcs, off, bsums, cnt, dis, b1, out, n, 0);

  // layer 2: g2 = dis * bf16(out @ W2) ; out = lrelu(dis*(sum g2 + g2_self) + b2)
  gemm_mfma_kernel<<<gGemm, 256, 0, stream>>>(out, wfrag + 32768, dis, bufG, n);
  agg_kernel<<<gAgg, 1024, 0, stream>>>(bufG, srcs, off, bsums, cnt, dis, b2, out, n, 1);
}